// Round 1
// baseline (125.163 us; speedup 1.0000x reference)
//
#include <hip/hip_runtime.h>

// MaddnessMatmul: N=262144 rows, D=64, C=16 codebooks, K=16 protos, M=16 outputs.
// out[m][n] = sum_c luts[c][enc(n,c)][m],  luts[c][k][m] = dot(B[m], P[c][k]).
//
// Design (round 1):
//  - fused phase0: each block computes the 4096-entry LUT into LDS (padded k-stride 20
//    so b128 LUT gathers are <=2-way bank aliased = free).
//  - A staged per 128-row tile into LDS, row stride 65 (encode gathers conflict-free),
//    loaded with fully coalesced float4 reads, register-prefetched one tile ahead so
//    HBM streaming overlaps compute.
//  - encode levels 0/1 use wave-uniform global reads (s_load) + cndmask selects;
//    levels 2/3 read the 2KB split_vals table in LDS (broadcast-friendly banks).
//  - 512 blocks x 4 tiles x 128 rows = 262144; 2 blocks/CU (55.8KB LDS each).

#define NROWS 262144
#define DDIM  64
#define CNUM  16
#define KPROT 16
#define MOUT  16
#define TPB   128
#define TILE  128
#define TILES_PER_BLOCK 4
#define NBLOCKS 512          // 512 * 4 * 128 = 262144
#define LSTRIDE 20           // padded LUT k-stride (floats)
#define RSTRIDE 65           // padded LDS row stride (floats)

__global__ __launch_bounds__(TPB) void maddness_kernel(
    const float* __restrict__ A,
    const float* __restrict__ B,
    const float* __restrict__ P,
    const int*   __restrict__ sd,   // split_dims  [C][4]
    const float* __restrict__ sv,   // split_vals  [C][4][8]
    float* __restrict__ out)        // [M][NROWS]
{
    __shared__ __align__(16) float lut_s[CNUM * KPROT * LSTRIDE]; // 5120 f
    __shared__ __align__(16) float sv_s[CNUM * 32];               // 512 f
    __shared__ __align__(16) float rows_s[TILE * RSTRIDE];        // 8320 f

    const int t = threadIdx.x;

    // ---------------- phase 0: build LUT in LDS ----------------
    {
        const int m = t & 15;
        float4 brow[16];
        const float4* B4 = (const float4*)(B + m * DDIM);
        #pragma unroll
        for (int j = 0; j < 16; ++j) brow[j] = B4[j];

        #pragma unroll
        for (int j = 0; j < 32; ++j) {
            int o = j * TPB + t;          // 0..4095, bijective over (c,k,m)
            int c = o >> 8;
            int k = (o >> 4) & 15;
            const float4* P4 = (const float4*)(P + (c * KPROT + k) * DDIM);
            float dot = 0.f;
            #pragma unroll
            for (int q = 0; q < 16; ++q) {
                float4 p = P4[q];
                dot += p.x * brow[q].x + p.y * brow[q].y
                     + p.z * brow[q].z + p.w * brow[q].w;
            }
            lut_s[(c * KPROT + k) * LSTRIDE + m] = dot;
        }
        // stage split_vals (512 floats = 128 float4, one per thread)
        ((float4*)sv_s)[t] = ((const float4*)sv)[t];
    }

    // ---------------- prologue: prefetch tile 0 ----------------
    const float4* A4 = (const float4*)A;
    float4 R[16];
    {
        long base = (long)blockIdx.x * (TILE * DDIM / 4);
        #pragma unroll
        for (int j = 0; j < 16; ++j) R[j] = A4[base + j * TPB + t];
    }

    for (int s = 0; s < TILES_PER_BLOCK; ++s) {
        const int tile = blockIdx.x + s * NBLOCKS;

        __syncthreads();  // prev compute done with rows_s (and phase0 LUT for s=0)

        // scatter prefetched tile into LDS (banks (row+4*(e&15)+jj)%32: 2-way = free)
        #pragma unroll
        for (int j = 0; j < 16; ++j) {
            int e   = j * TPB + t;
            int row = e >> 4;
            int col = (e & 15) * 4;
            float* dst = &rows_s[row * RSTRIDE + col];
            float4 v = R[j];
            dst[0] = v.x; dst[1] = v.y; dst[2] = v.z; dst[3] = v.w;
        }
        // issue next tile's loads; in flight during compute below
        if (s + 1 < TILES_PER_BLOCK) {
            long base = (long)(tile + NBLOCKS) * (TILE * DDIM / 4);
            #pragma unroll
            for (int j = 0; j < 16; ++j) R[j] = A4[base + j * TPB + t];
        }

        __syncthreads();

        // ---------------- compute: one row per thread ----------------
        float acc[MOUT];
        #pragma unroll
        for (int m = 0; m < MOUT; ++m) acc[m] = 0.f;

        const float* rrow = &rows_s[t * RSTRIDE];

        #pragma unroll
        for (int c = 0; c < CNUM; ++c) {
            // wave-uniform scalar loads (compiler -> s_load, hoisted)
            const int   sd0 = sd[c * 4 + 0], sd1 = sd[c * 4 + 1];
            const int   sd2 = sd[c * 4 + 2], sd3 = sd[c * 4 + 3];
            const float v0  = sv[c * 32 + 0];
            const float v1a = sv[c * 32 + 8];
            const float v1b = sv[c * 32 + 9];

            int g = (rrow[sd0] > v0) ? 1 : 0;
            float v1 = g ? v1b : v1a;
            g = (g << 1) | ((rrow[sd1] > v1) ? 1 : 0);
            float v2 = sv_s[c * 32 + 16 + g];
            g = (g << 1) | ((rrow[sd2] > v2) ? 1 : 0);
            float v3 = sv_s[c * 32 + 24 + g];
            g = (g << 1) | ((rrow[sd3] > v3) ? 1 : 0);

            const float4* lp = (const float4*)&lut_s[(c * KPROT + g) * LSTRIDE];
            float4 p0 = lp[0], p1 = lp[1], p2 = lp[2], p3 = lp[3];
            acc[0]  += p0.x; acc[1]  += p0.y; acc[2]  += p0.z; acc[3]  += p0.w;
            acc[4]  += p1.x; acc[5]  += p1.y; acc[6]  += p1.z; acc[7]  += p1.w;
            acc[8]  += p2.x; acc[9]  += p2.y; acc[10] += p2.z; acc[11] += p2.w;
            acc[12] += p3.x; acc[13] += p3.y; acc[14] += p3.z; acc[15] += p3.w;
        }

        const int n = tile * TILE + t;
        #pragma unroll
        for (int m = 0; m < MOUT; ++m)
            out[(long)m * NROWS + n] = acc[m];
    }
}

extern "C" void kernel_launch(void* const* d_in, const int* in_sizes, int n_in,
                              void* d_out, int out_size, void* d_ws, size_t ws_size,
                              hipStream_t stream) {
    const float* A  = (const float*)d_in[0];
    const float* B  = (const float*)d_in[1];
    const float* P  = (const float*)d_in[2];
    const int*   sd = (const int*)d_in[3];
    const float* sv = (const float*)d_in[4];
    float* out = (float*)d_out;

    maddness_kernel<<<dim3(NBLOCKS), dim3(TPB), 0, stream>>>(A, B, P, sd, sv, out);
}

// Round 2
// 124.177 us; speedup vs baseline: 1.0079x; 1.0079x over previous
//
#include <hip/hip_runtime.h>
#include <hip/hip_fp16.h>

// MaddnessMatmul round 2.
// Problem: N=262144 rows, D=64, C=16 codebooks, K=16 protos, M=16 outputs.
//   out[m][n] = sum_c luts[c][enc(n,c)][m],  luts[c][k][m] = dot(B[m], P[c][k]).
//
// R1 post-mortem: 44-47us, Occupancy 9.4%, VALUBusy 16% -> latency-bound at
// 1 wave/SIMD (55.8KB LDS -> 2 blocks/CU). R2 design:
//  - lut_build kernel: 4096 threads compute f16 LUT -> d_ws (8KB). Removes the
//    per-block 2048-FMA phase0 so the main grid can be 2048 blocks.
//  - main: 128 thr/block, 128 rows/block, LDS 45.3KB -> 3 blocks/CU, 6 waves/CU.
//    * A tile transposed in LDS at col*129+row: encode gather (lanes=rows,
//      col uniform) conflict-free; scatter writes 2-way (free).
//    * LUT f16 in LDS, 24-half entry stride: 2 b128/codebook, <=2-way banks.
//    * split_vals via wave-uniform scalar loads + cndmask trees (no LDS
//      round-trip in the encode dependency chain; all 4 gathers/c issue early).
//    * accumulate in 2 interleaved f16 partial sums (v_pk_add_f16), combine in
//      f32 at epilogue (worst added err ~1 << 3.6 threshold).

#define NROWS 262144
#define DDIM  64
#define TPB   128
#define NBLK  2048        // 2048 * 128 = 262144
#define RSTR  129         // LDS floats per column (>=128 rows, odd -> no conflicts)
#define LSTR  24          // LDS halfs per LUT entry (48B: b128 banks <=2-way)

typedef __attribute__((ext_vector_type(8))) _Float16 half8;
typedef __attribute__((ext_vector_type(4))) unsigned int u32x4;

__global__ __launch_bounds__(256) void lut_build(
    const float* __restrict__ B,      // [16][64]
    const float* __restrict__ P,      // [16][16][64]
    _Float16* __restrict__ lutw)      // [16][16][16] = c,k,m
{
    int o = blockIdx.x * 256 + threadIdx.x;   // o = c*256 + k*16 + m
    int m  = o & 15;
    int ck = o >> 4;
    const float4* Bp = (const float4*)(B + m * DDIM);
    const float4* Pp = (const float4*)(P + ck * DDIM);
    float dot = 0.f;
    #pragma unroll
    for (int q = 0; q < 16; ++q) {
        float4 b = Bp[q], p = Pp[q];
        dot += b.x * p.x + b.y * p.y + b.z * p.z + b.w * p.w;
    }
    lutw[o] = (_Float16)dot;
}

__global__ __launch_bounds__(TPB, 2) void maddness_main(
    const float* __restrict__ A,      // [N][64]
    const int*   __restrict__ sd,     // [16][4]
    const float* __restrict__ sv,     // [16][4][8]
    const _Float16* __restrict__ lutw,// [16][16][16]
    float* __restrict__ out)          // [16][N]
{
    __shared__ float rows_s[DDIM * RSTR];                  // 33,024 B
    __shared__ __align__(16) _Float16 lut_s[256 * LSTR];   // 12,288 B

    const int t = threadIdx.x;

    // ---- copy LUT (8KB) into LDS, padded stride 24 halfs ----
    #pragma unroll
    for (int i = 0; i < 2; ++i) {
        int e = t + i * TPB;                      // entry 0..255
        const u32x4* src = (const u32x4*)(lutw + e * 16);
        u32x4 q0 = src[0], q1 = src[1];
        *(u32x4*)(lut_s + e * LSTR)     = q0;
        *(u32x4*)(lut_s + e * LSTR + 8) = q1;
    }

    // ---- stage A tile (128 rows), transposed: LDS[col*129 + row] ----
    const float4* A4 = (const float4*)A;
    long base = (long)blockIdx.x * (TPB * DDIM / 4);
    float4 R[16];
    #pragma unroll
    for (int j = 0; j < 16; ++j) R[j] = A4[base + j * TPB + t];
    #pragma unroll
    for (int j = 0; j < 16; ++j) {
        int f    = j * TPB + t;        // float4 index within tile
        int row  = f >> 4;
        int colq = (f & 15) * 4;
        rows_s[(colq + 0) * RSTR + row] = R[j].x;
        rows_s[(colq + 1) * RSTR + row] = R[j].y;
        rows_s[(colq + 2) * RSTR + row] = R[j].z;
        rows_s[(colq + 3) * RSTR + row] = R[j].w;
    }

    __syncthreads();

    // ---- encode + LUT-accumulate; thread t owns tile row t ----
    half8 aE0 = {0,0,0,0,0,0,0,0}, aE1 = {0,0,0,0,0,0,0,0};
    half8 aO0 = {0,0,0,0,0,0,0,0}, aO1 = {0,0,0,0,0,0,0,0};

    #pragma unroll
    for (int c = 0; c < 16; ++c) {
        const int sd0 = sd[c*4+0], sd1 = sd[c*4+1], sd2 = sd[c*4+2], sd3 = sd[c*4+3];
        // all 4 gathers have compare-independent addresses -> issue up front
        float x0 = rows_s[sd0 * RSTR + t];
        float x1 = rows_s[sd1 * RSTR + t];
        float x2 = rows_s[sd2 * RSTR + t];
        float x3 = rows_s[sd3 * RSTR + t];
        const float* svc = sv + c * 32;

        int g = (x0 > svc[0]) ? 1 : 0;
        float v1 = g ? svc[9] : svc[8];
        g = (g << 1) | ((x1 > v1) ? 1 : 0);
        float ta = (g & 1) ? svc[17] : svc[16];
        float tb = (g & 1) ? svc[19] : svc[18];
        float v2 = (g & 2) ? tb : ta;
        g = (g << 1) | ((x2 > v2) ? 1 : 0);
        float u0 = (g & 1) ? svc[25] : svc[24];
        float u1 = (g & 1) ? svc[27] : svc[26];
        float u2 = (g & 1) ? svc[29] : svc[28];
        float u3 = (g & 1) ? svc[31] : svc[30];
        float w0 = (g & 2) ? u1 : u0;
        float w1 = (g & 2) ? u3 : u2;
        float v3 = (g & 4) ? w1 : w0;
        g = (g << 1) | ((x3 > v3) ? 1 : 0);

        const _Float16* lp = lut_s + (c * 16 + g) * LSTR;
        half8 l0 = *(const half8*)(lp);
        half8 l1 = *(const half8*)(lp + 8);
        if (c & 1) { aO0 += l0; aO1 += l1; }
        else       { aE0 += l0; aE1 += l1; }
    }

    const int n = blockIdx.x * TPB + t;
    #pragma unroll
    for (int m = 0; m < 8; ++m) {
        out[(long)m       * NROWS + n] = (float)aE0[m] + (float)aO0[m];
        out[(long)(m + 8) * NROWS + n] = (float)aE1[m] + (float)aO1[m];
    }
}

extern "C" void kernel_launch(void* const* d_in, const int* in_sizes, int n_in,
                              void* d_out, int out_size, void* d_ws, size_t ws_size,
                              hipStream_t stream) {
    const float* A  = (const float*)d_in[0];
    const float* B  = (const float*)d_in[1];
    const float* P  = (const float*)d_in[2];
    const int*   sd = (const int*)d_in[3];
    const float* sv = (const float*)d_in[4];
    float* out = (float*)d_out;
    _Float16* lutw = (_Float16*)d_ws;     // 8KB scratch for the f16 LUT

    lut_build<<<dim3(16), dim3(256), 0, stream>>>(B, P, lutw);
    maddness_main<<<dim3(NBLK), dim3(TPB), 0, stream>>>(A, sd, sv, lutw, out);
}

// Round 3
// 122.162 us; speedup vs baseline: 1.0246x; 1.0165x over previous
//
#include <hip/hip_runtime.h>
#include <hip/hip_fp16.h>

// MaddnessMatmul round 3.
//   out[m][n] = sum_c luts[c][enc(n,c)][m],  luts[c][k][m] = dot(B[m], P[c][k]).
//
// R2 post-mortem: 42us, Occupancy 12.5% (4 waves/CU), VALUBusy 11% -> latency
// bound. R3: amortize the replicated 12KB LUT over bigger blocks:
//  - TPB=256, 256 rows/block, 2 tiles/block (512 blocks).
//  - A tile transposed in LDS, column stride 261 floats:
//      gather  rows_s[sd*261+t]      -> bank (5*sd+t)%32, 2-way = free
//      scatter rows_s[(c)*261+row]   -> 32 banks x 2 lanes = free
//  - LDS = 66,816 (A) + 12,288 (f16 LUT, stride 24 halfs) = 79.1KB
//      -> 2 blocks/CU = 16 waves/CU (was 4).
//  - register prefetch of next tile (16 float4/thread) overlaps HBM with compute.
//  - encode: split_dims/vals via wave-uniform s_loads + cndmask trees; all 4
//    LDS gathers per codebook issue before the compare chain.
//  - accumulate 2 interleaved f16 partial sums (v_pk_add_f16), f32 combine at
//    epilogue (adds ~<1 err, threshold 3.6).

#define NROWS 262144
#define DDIM  64
#define TPB   256
#define ROWS  256
#define TILES 2
#define NBLK  512         // 512 * 2 * 256 = 262144
#define CSTR  261         // LDS floats per column (odd-ish: 5s+t bank spread)
#define LSTR  24          // LDS halfs per LUT entry

typedef __attribute__((ext_vector_type(8))) _Float16 half8;
typedef __attribute__((ext_vector_type(4))) unsigned int u32x4;

__global__ __launch_bounds__(256) void lut_build(
    const float* __restrict__ B,      // [16][64]
    const float* __restrict__ P,      // [16][16][64]
    _Float16* __restrict__ lutw)      // [16][16][16] = c,k,m
{
    int o = blockIdx.x * 256 + threadIdx.x;   // o = c*256 + k*16 + m
    int m  = o & 15;
    int ck = o >> 4;
    const float4* Bp = (const float4*)(B + m * DDIM);
    const float4* Pp = (const float4*)(P + ck * DDIM);
    float dot = 0.f;
    #pragma unroll
    for (int q = 0; q < 16; ++q) {
        float4 b = Bp[q], p = Pp[q];
        dot += b.x * p.x + b.y * p.y + b.z * p.z + b.w * p.w;
    }
    lutw[o] = (_Float16)dot;
}

__global__ __launch_bounds__(TPB, 2) void maddness_main(
    const float* __restrict__ A,      // [N][64]
    const int*   __restrict__ sd,     // [16][4]
    const float* __restrict__ sv,     // [16][4][8]
    const _Float16* __restrict__ lutw,// [16][16][16]
    float* __restrict__ out)          // [16][N]
{
    __shared__ float rows_s[DDIM * CSTR];                  // 66,816 B
    __shared__ __align__(16) _Float16 lut_s[256 * LSTR];   // 12,288 B

    const int t = threadIdx.x;

    // ---- copy f16 LUT (8KB) into LDS, padded stride 24 halfs ----
    {
        const u32x4* src = (const u32x4*)(lutw + t * 16);
        u32x4 q0 = src[0], q1 = src[1];
        *(u32x4*)(lut_s + t * LSTR)     = q0;
        *(u32x4*)(lut_s + t * LSTR + 8) = q1;
    }

    // ---- prologue: prefetch tile 0 (256 rows = 4096 float4) ----
    const float4* A4 = (const float4*)A;
    float4 R[16];
    {
        long base = (long)blockIdx.x * (ROWS * DDIM / 4);
        #pragma unroll
        for (int j = 0; j < 16; ++j) R[j] = A4[base + j * TPB + t];
    }

    for (int s = 0; s < TILES; ++s) {
        const int tile = blockIdx.x + s * NBLK;

        __syncthreads();   // prev compute done with rows_s

        // scatter prefetched tile into LDS, transposed: [col*261 + row]
        #pragma unroll
        for (int j = 0; j < 16; ++j) {
            int f    = j * TPB + t;        // float4 index in tile
            int row  = f >> 4;
            int colq = (f & 15) * 4;
            rows_s[(colq + 0) * CSTR + row] = R[j].x;
            rows_s[(colq + 1) * CSTR + row] = R[j].y;
            rows_s[(colq + 2) * CSTR + row] = R[j].z;
            rows_s[(colq + 3) * CSTR + row] = R[j].w;
        }
        // issue next tile's global loads; in flight during compute below
        if (s + 1 < TILES) {
            long base = (long)(tile + NBLK) * (ROWS * DDIM / 4);
            #pragma unroll
            for (int j = 0; j < 16; ++j) R[j] = A4[base + j * TPB + t];
        }

        __syncthreads();

        // ---- encode + LUT-accumulate; thread t owns tile row t ----
        half8 aE0 = {0,0,0,0,0,0,0,0}, aE1 = {0,0,0,0,0,0,0,0};
        half8 aO0 = {0,0,0,0,0,0,0,0}, aO1 = {0,0,0,0,0,0,0,0};

        #pragma unroll
        for (int c = 0; c < 16; ++c) {
            const int sd0 = sd[c*4+0], sd1 = sd[c*4+1];
            const int sd2 = sd[c*4+2], sd3 = sd[c*4+3];
            // compare-independent addresses -> all 4 gathers issue up front
            float x0 = rows_s[sd0 * CSTR + t];
            float x1 = rows_s[sd1 * CSTR + t];
            float x2 = rows_s[sd2 * CSTR + t];
            float x3 = rows_s[sd3 * CSTR + t];
            const float* svc = sv + c * 32;

            int g = (x0 > svc[0]) ? 1 : 0;
            float v1 = g ? svc[9] : svc[8];
            g = (g << 1) | ((x1 > v1) ? 1 : 0);
            float ta = (g & 1) ? svc[17] : svc[16];
            float tb = (g & 1) ? svc[19] : svc[18];
            float v2 = (g & 2) ? tb : ta;
            g = (g << 1) | ((x2 > v2) ? 1 : 0);
            float u0 = (g & 1) ? svc[25] : svc[24];
            float u1 = (g & 1) ? svc[27] : svc[26];
            float u2 = (g & 1) ? svc[29] : svc[28];
            float u3 = (g & 1) ? svc[31] : svc[30];
            float w0 = (g & 2) ? u1 : u0;
            float w1 = (g & 2) ? u3 : u2;
            float v3 = (g & 4) ? w1 : w0;
            g = (g << 1) | ((x3 > v3) ? 1 : 0);

            const _Float16* lp = lut_s + (c * 16 + g) * LSTR;
            half8 l0 = *(const half8*)(lp);
            half8 l1 = *(const half8*)(lp + 8);
            if (c & 1) { aO0 += l0; aO1 += l1; }
            else       { aE0 += l0; aE1 += l1; }
        }

        const int n = tile * ROWS + t;
        #pragma unroll
        for (int m = 0; m < 8; ++m) {
            out[(long)m       * NROWS + n] = (float)aE0[m] + (float)aO0[m];
            out[(long)(m + 8) * NROWS + n] = (float)aE1[m] + (float)aO1[m];
        }
    }
}

extern "C" void kernel_launch(void* const* d_in, const int* in_sizes, int n_in,
                              void* d_out, int out_size, void* d_ws, size_t ws_size,
                              hipStream_t stream) {
    const float* A  = (const float*)d_in[0];
    const float* B  = (const float*)d_in[1];
    const float* P  = (const float*)d_in[2];
    const int*   sd = (const int*)d_in[3];
    const float* sv = (const float*)d_in[4];
    float* out = (float*)d_out;
    _Float16* lutw = (_Float16*)d_ws;     // 8KB scratch for the f16 LUT

    lut_build<<<dim3(16), dim3(256), 0, stream>>>(B, P, lutw);
    maddness_main<<<dim3(NBLK), dim3(TPB), 0, stream>>>(A, sd, sv, lutw, out);
}

// Round 4
// 111.661 us; speedup vs baseline: 1.1209x; 1.0940x over previous
//
#include <hip/hip_runtime.h>
#include <hip/hip_fp16.h>

// MaddnessMatmul round 4.
//   out[m][n] = sum_c luts[c][enc(n,c)][m],  luts[c][k][m] = dot(B[m], P[c][k]).
//
// R3 post-mortem: main ~40us despite 8 waves/CU. Root cause theory: the encode
// needed 17 wave-uniform scalars per codebook (272 words total) -> compiler
// re-issues s_loads + lgkmcnt waits inside every unrolled c-iteration.
// R4: thresholds come from LDS by *index* (v = sv_s[c*32+8*lvl+g], <=8 distinct
// addresses on distinct banks = free), killing in-loop scalar traffic; only sd
// (64 SGPRs) stays scalar and hoists as one batched load. A tile back to
// row-major stride 65 (gather bank (t+sd)%32 2-way free; scatter 2-way free).
// LDS 80,896B -> 2 blocks/CU, 8 waves/CU; 2-tile register prefetch overlaps HBM.

#define NROWS 262144
#define DDIM  64
#define TPB   256
#define ROWS  256
#define TILES 2
#define NBLK  512         // 512 * 2 * 256 = 262144
#define RSTR  65          // row-major LDS stride (floats)
#define LSTR  24          // halfs per LUT entry (48B: 16B-aligned, banks <=2-way)

typedef __attribute__((ext_vector_type(8))) _Float16 half8;
typedef __attribute__((ext_vector_type(4))) unsigned int u32x4;

__global__ __launch_bounds__(256) void lut_build(
    const float* __restrict__ B,      // [16][64]
    const float* __restrict__ P,      // [16][16][64]
    _Float16* __restrict__ lutw)      // [16][16][16] = c,k,m
{
    int o = blockIdx.x * 256 + threadIdx.x;   // o = c*256 + k*16 + m
    int m  = o & 15;
    int ck = o >> 4;
    const float4* Bp = (const float4*)(B + m * DDIM);
    const float4* Pp = (const float4*)(P + ck * DDIM);
    float dot = 0.f;
    #pragma unroll
    for (int q = 0; q < 16; ++q) {
        float4 b = Bp[q], p = Pp[q];
        dot += b.x * p.x + b.y * p.y + b.z * p.z + b.w * p.w;
    }
    lutw[o] = (_Float16)dot;
}

__global__ __launch_bounds__(TPB, 2) void maddness_main(
    const float* __restrict__ A,      // [N][64]
    const int*   __restrict__ sd,     // [16][4]
    const float* __restrict__ sv,     // [16][4][8]
    const _Float16* __restrict__ lutw,// [16][16][16]
    float* __restrict__ out)          // [16][N]
{
    __shared__ float rows_s[ROWS * RSTR];                  // 66,560 B
    __shared__ __align__(16) _Float16 lut_s[256 * LSTR];   // 12,288 B
    __shared__ float sv_s[512];                            //  2,048 B

    const int t = threadIdx.x;

    // ---- stage f16 LUT (8KB) into LDS, stride 24 halfs ----
    {
        const u32x4* src = (const u32x4*)(lutw + t * 16);
        u32x4 q0 = src[0], q1 = src[1];
        *(u32x4*)(lut_s + t * LSTR)     = q0;
        *(u32x4*)(lut_s + t * LSTR + 8) = q1;
    }
    // ---- stage split_vals (512 floats) ----
    {
        float2 v = ((const float2*)sv)[t];
        ((float2*)sv_s)[t] = v;
    }

    // ---- prologue: prefetch tile 0 (256 rows = 4096 float4) ----
    const float4* A4 = (const float4*)A;
    float4 R[16];
    {
        long base = (long)blockIdx.x * (ROWS * DDIM / 4);
        #pragma unroll
        for (int j = 0; j < 16; ++j) R[j] = A4[base + j * TPB + t];
    }

    for (int s = 0; s < TILES; ++s) {
        const int tile = blockIdx.x + s * NBLK;

        __syncthreads();   // prev compute done with rows_s

        // scatter prefetched tile into LDS, row-major stride 65
        // bank (row + colq + jj) % 32 -> 2 lanes/bank = free
        #pragma unroll
        for (int j = 0; j < 16; ++j) {
            int f    = j * TPB + t;        // float4 index in tile
            int row  = f >> 4;
            int colq = (f & 15) * 4;
            float* dst = &rows_s[row * RSTR + colq];
            dst[0] = R[j].x; dst[1] = R[j].y; dst[2] = R[j].z; dst[3] = R[j].w;
        }
        // issue next tile's global loads; in flight during compute below
        if (s + 1 < TILES) {
            long base = (long)(tile + NBLK) * (ROWS * DDIM / 4);
            #pragma unroll
            for (int j = 0; j < 16; ++j) R[j] = A4[base + j * TPB + t];
        }

        __syncthreads();

        // ---- encode + LUT-accumulate; thread t owns tile row t ----
        half8 aE0 = {0,0,0,0,0,0,0,0}, aE1 = {0,0,0,0,0,0,0,0};
        half8 aO0 = {0,0,0,0,0,0,0,0}, aO1 = {0,0,0,0,0,0,0,0};

        const float* rrow = &rows_s[t * RSTR];

        #pragma unroll
        for (int c = 0; c < 16; ++c) {
            // sd: 64 SGPRs total -> batched s_load_dwordx4, hoisted per tile
            const int sd0 = sd[c*4+0], sd1 = sd[c*4+1];
            const int sd2 = sd[c*4+2], sd3 = sd[c*4+3];
            // compare-independent addresses -> all 4 gathers issue up front
            float x0 = rrow[sd0];
            float x1 = rrow[sd1];
            float x2 = rrow[sd2];
            float x3 = rrow[sd3];

            // thresholds by index from LDS (broadcast-friendly, no scalars)
            int g = (x0 > sv_s[c*32]) ? 1 : 0;
            float v1 = sv_s[c*32 + 8 + g];
            g = (g << 1) | ((x1 > v1) ? 1 : 0);
            float v2 = sv_s[c*32 + 16 + g];
            g = (g << 1) | ((x2 > v2) ? 1 : 0);
            float v3 = sv_s[c*32 + 24 + g];
            g = (g << 1) | ((x3 > v3) ? 1 : 0);

            const _Float16* lp = lut_s + (c * 16 + g) * LSTR;
            half8 l0 = *(const half8*)(lp);
            half8 l1 = *(const half8*)(lp + 8);
            if (c & 1) { aO0 += l0; aO1 += l1; }
            else       { aE0 += l0; aE1 += l1; }
        }

        const int n = tile * ROWS + t;
        #pragma unroll
        for (int m = 0; m < 8; ++m) {
            out[(long)m       * NROWS + n] = (float)aE0[m] + (float)aO0[m];
            out[(long)(m + 8) * NROWS + n] = (float)aE1[m] + (float)aO1[m];
        }
    }
}

extern "C" void kernel_launch(void* const* d_in, const int* in_sizes, int n_in,
                              void* d_out, int out_size, void* d_ws, size_t ws_size,
                              hipStream_t stream) {
    const float* A  = (const float*)d_in[0];
    const float* B  = (const float*)d_in[1];
    const float* P  = (const float*)d_in[2];
    const int*   sd = (const int*)d_in[3];
    const float* sv = (const float*)d_in[4];
    float* out = (float*)d_out;
    _Float16* lutw = (_Float16*)d_ws;     // 8KB scratch for the f16 LUT

    lut_build<<<dim3(16), dim3(256), 0, stream>>>(B, P, lutw);
    maddness_main<<<dim3(NBLK), dim3(TPB), 0, stream>>>(A, sd, sv, lutw, out);
}

// Round 5
// 109.057 us; speedup vs baseline: 1.1477x; 1.0239x over previous
//
#include <hip/hip_runtime.h>
#include <hip/hip_fp16.h>

// MaddnessMatmul round 5: split encode / accumulate.
//   out[m][n] = sum_c luts[c][enc(n,c)][m],  luts[c][k][m] = dot(B[m], P[c][k]).
//
// R4 post-mortem: fused kernel ~30us at 8 waves/CU (81KB LDS) vs ~13us pipe
// floor -> latency-bound; the LUT-accumulate phase is trapped at A-staging
// occupancy. R5:
//  - encode_kernel: TPB=64 single-wave blocks (4096 blocks, 18.7KB LDS ->
//    8 blocks/CU), stages 64-row A tiles (row stride 65: gather bank (t+sd)%32
//    2-way = free), emits packed 4-bit codes (uint2/row, 2MB). Blocks 0..15
//    also build the f16 LUT -> d_ws (hidden under A-load latency).
//  - accum_kernel: no A tile, 12.3KB LDS -> 32 waves/CU (wave-capped). Reads
//    codes, 2x ds_read_b128 per codebook from the stride-24 f16 LUT, packed
//    f16 adds (even/odd c split, f32 combine: absmax ~1 << 3.6), writes 16MB.
//  - extra HBM for the code round-trip: 4MB (~0.6us) -- cheap vs occupancy win.

#define NROWS 262144
#define DDIM  64
#define RSTR  65          // LDS floats per staged row (odd -> conflict-free)
#define LSTR  24          // LDS halfs per LUT entry (48B, b128 banks <=2-way)
#define EBLK  4096        // encode blocks: 4096 * 64 rows = 262144
#define ABLK  1024        // accum blocks: 1024 * 256 rows = 262144

typedef __attribute__((ext_vector_type(8))) _Float16 half8;
typedef __attribute__((ext_vector_type(4))) unsigned int u32x4;

__global__ __launch_bounds__(64) void encode_kernel(
    const float* __restrict__ A,      // [N][64]
    const float* __restrict__ B,      // [16][64]
    const float* __restrict__ P,      // [16][16][64]
    const int*   __restrict__ sd,     // [16][4]
    const float* __restrict__ sv,     // [16][4][8]
    _Float16* __restrict__ lutw,      // [256][16] f16 (d_ws)
    uint2* __restrict__ codes)        // [N] packed 16x4-bit (d_ws+8KB)
{
    __shared__ float rows_s[64 * RSTR];   // 16,640 B
    __shared__ float sv_s[512];           //  2,048 B
    const int t = threadIdx.x;

    // stage split_vals (512 floats = 128 float4; 2 per thread)
    ((float4*)sv_s)[t]      = ((const float4*)sv)[t];
    ((float4*)sv_s)[t + 64] = ((const float4*)sv)[t + 64];

    // issue A tile loads (64 rows = 1024 float4, 16/thread, coalesced)
    const float4* A4 = (const float4*)A;
    long base = (long)blockIdx.x * (64 * DDIM / 4);
    float4 R[16];
    #pragma unroll
    for (int j = 0; j < 16; ++j) R[j] = A4[base + j * 64 + t];

    // fused LUT build on first 16 blocks (independent; overlaps A-load wait)
    if (blockIdx.x < 16) {
        const int m = t & 15;
        const float4* Bp = (const float4*)(B + m * DDIM);
        float4 brow[16];
        #pragma unroll
        for (int q = 0; q < 16; ++q) brow[q] = Bp[q];
        #pragma unroll
        for (int i = 0; i < 4; ++i) {
            int o  = blockIdx.x * 256 + i * 64 + t;   // c*256 + k*16 + m
            int ck = o >> 4;
            const float4* Pp = (const float4*)(P + ck * DDIM);
            float dot = 0.f;
            #pragma unroll
            for (int q = 0; q < 16; ++q) {
                float4 p = Pp[q];
                dot += p.x * brow[q].x + p.y * brow[q].y
                     + p.z * brow[q].z + p.w * brow[q].w;
            }
            lutw[o] = (_Float16)dot;
        }
    }

    // scatter tile into LDS, row-major stride 65 (2 lanes/bank = free)
    #pragma unroll
    for (int j = 0; j < 16; ++j) {
        int f    = j * 64 + t;
        int row  = f >> 4;
        int colq = (f & 15) * 4;
        float* dst = &rows_s[row * RSTR + colq];
        dst[0] = R[j].x; dst[1] = R[j].y; dst[2] = R[j].z; dst[3] = R[j].w;
    }
    __syncthreads();   // single wave: compiles to a cheap lgkmcnt drain

    // encode row t: 16 codebooks, 4 levels each; thresholds by LDS index
    const float* rrow = &rows_s[t * RSTR];
    unsigned int lo = 0, hi = 0;
    #pragma unroll
    for (int c = 0; c < 16; ++c) {
        const int sd0 = sd[c*4+0], sd1 = sd[c*4+1];
        const int sd2 = sd[c*4+2], sd3 = sd[c*4+3];
        float x0 = rrow[sd0];
        float x1 = rrow[sd1];
        float x2 = rrow[sd2];
        float x3 = rrow[sd3];
        int g = (x0 > sv_s[c*32]) ? 1 : 0;
        g = (g << 1) | ((x1 > sv_s[c*32 +  8 + g]) ? 1 : 0);
        g = (g << 1) | ((x2 > sv_s[c*32 + 16 + g]) ? 1 : 0);
        g = (g << 1) | ((x3 > sv_s[c*32 + 24 + g]) ? 1 : 0);
        if (c < 8) lo |= (unsigned)g << (4 * c);
        else       hi |= (unsigned)g << (4 * (c - 8));
    }
    codes[blockIdx.x * 64 + t] = make_uint2(lo, hi);
}

__global__ __launch_bounds__(256) void accum_kernel(
    const uint2* __restrict__ codes,  // [N]
    const _Float16* __restrict__ lutw,// [256][16] f16
    float* __restrict__ out)          // [16][N]
{
    __shared__ __align__(16) _Float16 lut_s[256 * LSTR];  // 12,288 B
    const int t = threadIdx.x;

    // stage LUT: one 32B entry per thread, padded stride 24 halfs
    {
        const u32x4* src = (const u32x4*)(lutw + t * 16);
        u32x4 q0 = src[0], q1 = src[1];
        *(u32x4*)(lut_s + t * LSTR)     = q0;
        *(u32x4*)(lut_s + t * LSTR + 8) = q1;
    }
    __syncthreads();

    const int n = blockIdx.x * 256 + t;
    const uint2 code = codes[n];

    half8 aE0 = {0,0,0,0,0,0,0,0}, aE1 = {0,0,0,0,0,0,0,0};
    half8 aO0 = {0,0,0,0,0,0,0,0}, aO1 = {0,0,0,0,0,0,0,0};

    #pragma unroll
    for (int c = 0; c < 8; ++c) {
        int g = (code.x >> (4 * c)) & 15;
        const _Float16* lp = lut_s + (c * 16 + g) * LSTR;
        half8 l0 = *(const half8*)(lp);
        half8 l1 = *(const half8*)(lp + 8);
        if (c & 1) { aO0 += l0; aO1 += l1; }
        else       { aE0 += l0; aE1 += l1; }
    }
    #pragma unroll
    for (int c = 8; c < 16; ++c) {
        int g = (code.y >> (4 * (c - 8))) & 15;
        const _Float16* lp = lut_s + (c * 16 + g) * LSTR;
        half8 l0 = *(const half8*)(lp);
        half8 l1 = *(const half8*)(lp + 8);
        if (c & 1) { aO0 += l0; aO1 += l1; }
        else       { aE0 += l0; aE1 += l1; }
    }

    #pragma unroll
    for (int m = 0; m < 8; ++m) {
        out[(long)m       * NROWS + n] = (float)aE0[m] + (float)aO0[m];
        out[(long)(m + 8) * NROWS + n] = (float)aE1[m] + (float)aO1[m];
    }
}

extern "C" void kernel_launch(void* const* d_in, const int* in_sizes, int n_in,
                              void* d_out, int out_size, void* d_ws, size_t ws_size,
                              hipStream_t stream) {
    const float* A  = (const float*)d_in[0];
    const float* B  = (const float*)d_in[1];
    const float* P  = (const float*)d_in[2];
    const int*   sd = (const int*)d_in[3];
    const float* sv = (const float*)d_in[4];
    float* out = (float*)d_out;

    _Float16* lutw = (_Float16*)d_ws;                 // 8 KB f16 LUT
    uint2*    codes = (uint2*)((char*)d_ws + 8192);   // 2 MB packed codes

    encode_kernel<<<dim3(EBLK), dim3(64), 0, stream>>>(A, B, P, sd, sv, lutw, codes);
    accum_kernel<<<dim3(ABLK), dim3(256), 0, stream>>>(codes, lutw, out);
}